// Round 10
// baseline (145.846 us; speedup 1.0000x reference)
//
#include <hip/hip_runtime.h>
#include <math.h>

// TOF PET forward projection.
// History: R3 97us proj / FETCH 215MB -> R4 Morton sort: FETCH 26MB -> R5
// bucket atomic-storm bug -> R6 4 lanes/LOR: 67us -> R7 sorted ray records +
// 8 lanes/LOR: 50us, VGPR=16 -> R8 in-iteration load pairing: NEUTRAL (52us,
// VGPR still 16 — compiler won't hold 2 gathers in flight within one iter).
// R9: (a) explicit 1-deep software pipeline: iteration k issues the gather
// for k+1 before consuming gather k (load->use crosses the backedge), SPL=16
// for 2x TLP; (b) aux diet: tmp[] dropped (scatter recomputes key via shared
// helper), NBUCK 8192, smaller memset/scan.
// Index-path math is STRICTLY UNFUSED exact-rn f32 (numpy semantics) — DO NOT
// approximate or contract (R0-R2: FMA/ulp deviations => voxel flips =>
// absmax 0.14 > 0.071). fp contract(off); voxel /3.125 stays IEEE '/';
// /128 as *0.0078125f is bit-identical (pow2). Reciprocal-mul for /3.125 was
// analyzed and REJECTED (floor(rn(X/3.125)) flips ~1e-4/sample vs exact).
// Summation order is free (R4-R8 all at the bf16 comparison floor).

#define NB_POS 4096          // 16^3 Morton cells, 25 mm
#define NCLS   2             // window-length classes
#define NBUCK  (NB_POS * NCLS)
#define SPL    16            // lanes per LOR

__device__ __forceinline__ int morton4(int x, int y, int z) {
    int m = 0;
#pragma unroll
    for (int b = 0; b < 4; ++b) {
        m |= ((x >> b) & 1) << (3 * b + 0);
        m |= ((y >> b) & 1) << (3 * b + 1);
        m |= ((z >> b) & 1) << (3 * b + 2);
    }
    return m;
}

// Slab clip (strictly unfused, exact rn divs — produces the tmin/tmax the
// reference sees).
__device__ __forceinline__ void slab_clip(
    float p1x, float p1y, float p1z, float dx, float dy, float dz,
    float& tmin, float& tmax)
{
    const float eps = 1e-8f;
    float sdx = (fabsf(dx) < eps) ? eps : dx;
    float sdy = (fabsf(dy) < eps) ? eps : dy;
    float sdz = (fabsf(dz) < eps) ? eps : dz;
    float tax = (-200.f - p1x) / sdx, tbx = (200.f - p1x) / sdx;
    float tay = (-200.f - p1y) / sdy, tby = (200.f - p1y) / sdy;
    float taz = (-200.f - p1z) / sdz, tbz = (200.f - p1z) / sdz;
    tmin = fmaxf(fmaxf(fmaxf(fminf(tax, tbx), fminf(tay, tby)),
                       fminf(taz, tbz)), 0.f);
    tmax = fminf(fminf(fminf(fmaxf(tax, tbx), fmaxf(tay, tby)),
                       fmaxf(taz, tbz)), 1.f);
}

// Sort key — MUST be computed identically in bucket and scatter (shared).
// Approx math is fine here (affects only ordering, never values).
__device__ __forceinline__ unsigned sort_key(
    int i, float p1x, float p1y, float p1z,
    float dx, float dy, float dz, float tt, float L,
    float tmin, float tmax)
{
    if (!(tmax > tmin) || !(L > 0.f)) {
        // Invalids: spread uniformly (kills R5's one-bucket atomic storm).
        return (unsigned)i & (NBUCK - 1);
    }
    float span = tmax - tmin;
    float tc = fminf(fmaxf(0.5f + tt / L, tmin), tmax);
    float px = p1x + tc * dx, py = p1y + tc * dy, pz = p1z + tc * dz;
    int cx = (int)fminf(fmaxf((px + 200.f) * 0.04f, 0.f), 15.f);
    int cy = (int)fminf(fmaxf((py + 200.f) * 0.04f, 0.f), 15.f);
    int cz = (int)fminf(fmaxf((pz + 200.f) * 0.04f, 0.f), 15.f);
    float jl = ((0.5f + (tt - 90.f) / L) - tmin) / span * 128.f;
    float jh = ((0.5f + (tt + 90.f) / L) - tmin) / span * 128.f;
    jl = fmaxf(jl, 0.f); jh = fminf(jh, 128.f);
    float wlen = fmaxf(jh - jl, 0.f);
    int cls = (wlen > 64.f) ? 1 : 0;
    return ((unsigned)morton4(cx, cy, cz) << 1) | (unsigned)cls;
}

__global__ void bucket_kernel(const float* __restrict__ lors,
                              int* __restrict__ counts, int n) {
#pragma clang fp contract(off)
    int i = blockIdx.x * 256 + threadIdx.x;
    if (i >= n) return;
    const float* lp = lors + (size_t)i * 7;
    float p1x = lp[0], p1y = lp[1], p1z = lp[2];
    float dx = lp[3] - p1x, dy = lp[4] - p1y, dz = lp[5] - p1z;
    float tt = lp[6];
    float L = sqrtf(((dx * dx) + (dy * dy)) + (dz * dz));
    float tmin, tmax;
    slab_clip(p1x, p1y, p1z, dx, dy, dz, tmin, tmax);
    unsigned key = sort_key(i, p1x, p1y, p1z, dx, dy, dz, tt, L, tmin, tmax);
    atomicAdd(&counts[key], 1);
}

__global__ void scan_kernel(const int* __restrict__ counts,
                            int* __restrict__ offsets) {
    __shared__ int s[1024];
    int t = threadIdx.x;
    const int PER = NBUCK / 1024;
    int base = t * PER;
    int local[PER];
    int sum = 0;
#pragma unroll
    for (int i = 0; i < PER; ++i) { local[i] = counts[base + i]; sum += local[i]; }
    s[t] = sum;
    __syncthreads();
    for (int off = 1; off < 1024; off <<= 1) {
        int v = (t >= off) ? s[t - off] : 0;
        __syncthreads();
        s[t] += v;
        __syncthreads();
    }
    int excl = (t == 0) ? 0 : s[t - 1];
#pragma unroll
    for (int i = 0; i < PER; ++i) { offsets[base + i] = excl; excl += local[i]; }
}

// Scatter + setup: recomputes key (identical helper), computes per-LOR ray
// record once, writes SORTED record arrays.
__global__ void scatter_kernel(const float* __restrict__ lors,
                               int* __restrict__ offsets,
                               float4* __restrict__ recS,   // {tmin,span,L,pack}
                               float4* __restrict__ ls8,    // 2 per LOR
                               int n) {
#pragma clang fp contract(off)
    int i = blockIdx.x * 256 + threadIdx.x;
    if (i >= n) return;
    const float* lp = lors + (size_t)i * 7;
    float p1x = lp[0], p1y = lp[1], p1z = lp[2];
    float p2x = lp[3], p2y = lp[4], p2z = lp[5];
    float tt = lp[6];
    float dx = p2x - p1x, dy = p2y - p1y, dz = p2z - p1z;
    float L = sqrtf(((dx * dx) + (dy * dy)) + (dz * dz));

    float tmin, tmax;
    slab_clip(p1x, p1y, p1z, dx, dy, dz, tmin, tmax);
    unsigned key = sort_key(i, p1x, p1y, p1z, dx, dy, dz, tt, L, tmin, tmax);

    float span, recL;
    int jlo, jhi;
    if (!(tmax > tmin) || !(L > 0.f)) {
        // invalid or degenerate (step==0 => out 0 regardless)
        tmin = 0.f; span = 0.f; recL = 0.f; jlo = 0; jhi = -1;
    } else {
        span = tmax - tmin;
        recL = L;
        // Closed-form TOF sample range, +-2 slop (validated R4-R8); the exact
        // |dev|<=90 test in proj keeps the contributing set identical.
        const float tlo = 0.5f + (tt - 90.0f) / L;
        const float thi = 0.5f + (tt + 90.0f) / L;
        float jl = ((tlo - tmin) / span) * 128.0f - 0.5f;
        float jh = ((thi - tmin) / span) * 128.0f - 0.5f;
        jl = fminf(fmaxf(jl - 2.0f, 0.0f), 127.0f);
        jh = fminf(fmaxf(jh + 2.0f, -1.0f), 127.0f);
        jlo = (int)jl;
        jhi = (int)ceilf(jh);
        if (jhi > 127) jhi = 127;
    }

    int slot = atomicAdd(&offsets[key], 1);
    int pk = (jlo << 16) | (jhi & 0xFFFF);
    recS[slot] = make_float4(tmin, span, recL, __int_as_float(pk));
    ls8[2 * slot + 0] = make_float4(p1x, p1y, p1z, p2x);
    ls8[2 * slot + 1] = make_float4(p2y, p2z, tt, __int_as_float(i));
}

__global__ __launch_bounds__(256) void proj_kernel(
    const float* __restrict__ image,
    const float4* __restrict__ recS,
    const float4* __restrict__ ls8,
    float* __restrict__ out,
    int n_lors, int chunks)
{
#pragma clang fp contract(off)
    // XCD swizzle: block b -> XCD (b&7) works the (b&7)-th chunk of sorted order
    const int b = blockIdx.x;
    const int sb = (b & 7) * chunks + (b >> 3);
    const int idx = sb * 256 + (int)threadIdx.x;
    const int gid = idx >> 4;          // sorted LOR slot
    const int s   = idx & 15;          // sub-lane 0..15
    if (gid >= n_lors) return;

    const float4 a  = ls8[2 * gid + 0];
    const float4 c  = ls8[2 * gid + 1];
    const float4 r  = recS[gid];
    const float p1x = a.x, p1y = a.y, p1z = a.z;
    const float dx = a.w - p1x, dy = c.x - p1y, dz = c.y - p1z;
    const float ttof = c.z;
    const int   orig = __float_as_int(c.w);
    const float tmin = r.x, span = r.y, L = r.z;
    const int   pk   = __float_as_int(r.w);
    const int   jlo  = pk >> 16;
    const int   jhi  = (int)(short)(pk & 0xFFFF);

    float acc = 0.0f;
    const int j0 = jlo + s;
    if (j0 <= jhi) {
        // ---- prologue: sample j0 address + gather in flight ----
        const float frac0 = ((float)j0 + 0.5f) * 0.0078125f;   // exact
        float t_c = tmin + (frac0 * span);                      // UNFUSED
        {
        }
        const float px0 = p1x + (t_c * dx);                     // UNFUSED
        const float py0 = p1y + (t_c * dy);
        const float pz0 = p1z + (t_c * dz);
        int vx = (int)floorf((px0 + 200.0f) / 3.125f);          // exact rn div
        int vy = (int)floorf((py0 + 200.0f) / 3.125f);
        int vz = (int)floorf((pz0 + 200.0f) / 3.125f);
        vx = min(max(vx, 0), 127);
        vy = min(max(vy, 0), 127);
        vz = min(max(vz, 0), 127);
        float v_c = image[(((vx << 7) | vy) << 7) | vz];
        float dev_c = ((t_c - 0.5f) * L) - ttof;                // unfused

        // ---- steady state: issue gather k+1 before consuming gather k ----
        for (int jn = j0 + SPL; jn <= jhi; jn += SPL) {
            const float fracn = ((float)jn + 0.5f) * 0.0078125f;
            const float t_n = tmin + (fracn * span);            // UNFUSED
            const float pxn = p1x + (t_n * dx);                 // UNFUSED
            const float pyn = p1y + (t_n * dy);
            const float pzn = p1z + (t_n * dz);
            int vxn = (int)floorf((pxn + 200.0f) / 3.125f);     // exact rn div
            int vyn = (int)floorf((pyn + 200.0f) / 3.125f);
            int vzn = (int)floorf((pzn + 200.0f) / 3.125f);
            vxn = min(max(vxn, 0), 127);
            vyn = min(max(vyn, 0), 127);
            vzn = min(max(vzn, 0), 127);
            const float v_n = image[(((vxn << 7) | vyn) << 7) | vzn]; // in flight

            // consume sample k (weight path: invisible on bf16 grid)
            const float w = (fabsf(dev_c) <= 90.0f)
                ? 0.06649038f * __expf((dev_c * dev_c) * (-5.5555556e-4f))
                : 0.0f;
            acc += v_c * w;

            v_c = v_n;
            dev_c = ((t_n - 0.5f) * L) - ttof;                  // unfused
        }

        // ---- epilogue: consume last sample ----
        const float w = (fabsf(dev_c) <= 90.0f)
            ? 0.06649038f * __expf((dev_c * dev_c) * (-5.5555556e-4f))
            : 0.0f;
        acc += v_c * w;
    }

    // combine 16 sub-lanes (summation order free — validated R4-R8)
    acc += __shfl_xor(acc, 1, 64);
    acc += __shfl_xor(acc, 2, 64);
    acc += __shfl_xor(acc, 4, 64);
    acc += __shfl_xor(acc, 8, 64);

    if (s == 0) {
        const float step = (span * L) * 0.0078125f;   // /128 bit-identical
        out[orig] = acc * step;
    }
}

// Fallback (ws too small): self-contained thread-per-LOR, unsorted.
__global__ __launch_bounds__(256) void proj_fallback(
    const float* __restrict__ image,
    const float* __restrict__ lors,
    float* __restrict__ out, int n_lors)
{
#pragma clang fp contract(off)
    const int lor = blockIdx.x * 256 + threadIdx.x;
    if (lor >= n_lors) return;
    const float* lp = lors + (size_t)lor * 7;
    const float p1x = lp[0], p1y = lp[1], p1z = lp[2];
    const float dx = lp[3] - p1x, dy = lp[4] - p1y, dz = lp[5] - p1z;
    const float ttof = lp[6];
    const float L = sqrtf(((dx * dx) + (dy * dy)) + (dz * dz));
    float tmin, tmax;
    slab_clip(p1x, p1y, p1z, dx, dy, dz, tmin, tmax);
    const float span = fmaxf(tmax - tmin, 0.0f);
    if (!(tmax > tmin)) { out[lor] = 0.0f; return; }
    float acc = 0.0f;
    for (int j = 0; j < 128; ++j) {
        const float frac = ((float)j + 0.5f) * 0.0078125f;
        const float t = tmin + (frac * span);
        const float dev = ((t - 0.5f) * L) - ttof;
        if (fabsf(dev) <= 90.0f) {
            const float px = p1x + (t * dx);
            const float py = p1y + (t * dy);
            const float pz = p1z + (t * dz);
            int vx = (int)floorf((px + 200.0f) / 3.125f);
            int vy = (int)floorf((py + 200.0f) / 3.125f);
            int vz = (int)floorf((pz + 200.0f) / 3.125f);
            vx = min(max(vx, 0), 127);
            vy = min(max(vy, 0), 127);
            vz = min(max(vz, 0), 127);
            const float val = image[(((vx << 7) | vy) << 7) | vz];
            const float w = 0.06649038f *
                            __expf((dev * dev) * (-5.5555556e-4f));
            acc += val * w;
        }
    }
    out[lor] = acc * ((span * L) * 0.0078125f);
}

extern "C" void kernel_launch(void* const* d_in, const int* in_sizes, int n_in,
                              void* d_out, int out_size, void* d_ws, size_t ws_size,
                              hipStream_t stream) {
    const float* image = (const float*)d_in[0];   // 128^3 fp32
    const float* lors  = (const float*)d_in[1];   // N x 7 fp32
    float* out = (float*)d_out;                   // N fp32
    const int n = in_sizes[1] / 7;

    // ws layout: counts[NBUCK] | offsets[NBUCK] | (16B align) | recS[n]x16B |
    //            ls8[2n]x16B
    char* base = (char*)d_ws;
    int* counts  = (int*)base;
    int* offsets = counts + NBUCK;
    size_t off = (size_t)(2 * NBUCK) * sizeof(int);
    off = (off + 15) & ~(size_t)15;
    float4* recS = (float4*)(base + off);
    float4* ls8  = (float4*)(base + off + (size_t)n * 16);
    const size_t need = off + (size_t)n * 48;
    const bool do_sort = (ws_size >= need);

    if (do_sort) {
        hipMemsetAsync(counts, 0, NBUCK * sizeof(int), stream);
        bucket_kernel<<<(n + 255) / 256, 256, 0, stream>>>(lors, counts, n);
        scan_kernel<<<1, 1024, 0, stream>>>(counts, offsets);
        scatter_kernel<<<(n + 255) / 256, 256, 0, stream>>>(lors, offsets,
                                                            recS, ls8, n);
        const long long nthreads = (long long)n * SPL;
        const int nblocks = (int)((nthreads + 255) / 256);
        const int nb8 = ((nblocks + 7) / 8) * 8;
        proj_kernel<<<nb8, 256, 0, stream>>>(image, recS, ls8, out, n, nb8 >> 3);
    } else {
        proj_fallback<<<(n + 255) / 256, 256, 0, stream>>>(image, lors, out, n);
    }
}